// Round 3
// baseline (87.601 us; speedup 1.0000x reference)
//
#include <hip/hip_runtime.h>

namespace {
constexpr int NN = 320;
constexpr int DD = 64;
constexpr int N2 = NN * NN;          // 102400
constexpr long long N2D = (long long)N2 * DD;   // 6,553,600
constexpr long long N3 = (long long)N2 * NN;    // 32,768,000

// output offsets (floats)
constexpr long long O_K   = 0;
constexpr long long O_KXJ = O_K + N2;            //   102,400
constexpr long long O_KXI = O_KXJ + N2D;         // 6,656,000
constexpr long long O_TR  = O_KXI + N2D;         // 13,209,600
constexpr long long O_S4  = O_TR + N2;           // 13,312,000
constexpr long long O_T5  = O_S4 + N3;           // 46,080,000
constexpr long long O_VT  = O_T5 + N3;           // 78,848,000
}

// ---------------------------------------------------------------------------
// Kernel A: Gram matrices into scratch (= out1 region), c/scalars into out2
// grid = NN blocks, block = NN threads. Block i computes row i of 7 matrices.
// ---------------------------------------------------------------------------
__global__ __launch_bounds__(NN) void k_matrices(
        const float* __restrict__ x, const float* __restrict__ sigma,
        const float* __restrict__ score, const float* __restrict__ v,
        const float* __restrict__ gvs,
        float* __restrict__ s1,   // out1 region: 7 * N2 floats
        float* __restrict__ s2)   // out2 region: c[NN], gsum, g2sum
{
    __shared__ float xg[DD], xg2[DD], xg3[DD], sg[DD], sg2[DD], vg[DD], gg[DD];
    const int i = blockIdx.x;
    const int t = threadIdx.x;
    if (t < DD) {   // exactly wave 0
        float s  = sigma[t];
        float g  = 1.0f / (2.0f * s * s + 1e-8f);
        float g2 = g * g;
        float g3 = g2 * g;
        float xi = x[i * DD + t];
        xg[t]  = xi * g;  xg2[t] = xi * g2;  xg3[t] = xi * g3;
        float sc = score[i * DD + t];
        sg[t]  = sc * g;  sg2[t] = sc * g2;
        float vv = v[i * DD + t], gv = gvs[i * DD + t];
        vg[t] = vv * g;   gg[t] = gv * g;
        // c[i] = sum_d gamma*v*gvs  (64-lane wave reduce)
        float cp = g * vv * gv;
        #pragma unroll
        for (int off = 32; off; off >>= 1) cp += __shfl_down(cp, off, 64);
        if (t == 0) s2[i] = cp;
        if (i == 0) {
            float gs = g, g2s = g2;
            #pragma unroll
            for (int off = 32; off; off >>= 1) {
                gs  += __shfl_down(gs,  off, 64);
                g2s += __shfl_down(g2s, off, 64);
            }
            if (t == 0) { s2[NN] = gs; s2[NN + 1] = g2s; }
        }
    }
    __syncthreads();

    const int j = t;
    const float* xj = x + j * DD;
    float a1 = 0, a2 = 0, a3 = 0, a4 = 0, a5 = 0, a6 = 0, a7 = 0;
    #pragma unroll 8
    for (int d = 0; d < DD; ++d) {
        float xd = xj[d];
        a1 = fmaf(xg[d],  xd, a1);   // X1  = (x*g)   x^T
        a2 = fmaf(xg2[d], xd, a2);   // R   = (x*g2)  x^T
        a3 = fmaf(xg3[d], xd, a3);   // X3  = (x*g3)  x^T
        a4 = fmaf(sg[d],  xd, a4);   // P   = (sc*g)  x^T
        a5 = fmaf(sg2[d], xd, a5);   // T   = (sc*g2) x^T
        a6 = fmaf(vg[d],  xd, a6);   // AV  = (v*g)   x^T
        a7 = fmaf(gg[d],  xd, a7);   // BV  = (gvs*g) x^T
    }
    const int o = i * NN + j;
    s1[o]          = a1;
    s1[N2 + o]     = a2;
    s1[2 * N2 + o] = a3;
    s1[3 * N2 + o] = a4;
    s1[4 * N2 + o] = a5;
    s1[5 * N2 + o] = a6;
    s1[6 * N2 + o] = a7;
}

// ---------------------------------------------------------------------------
// Kernel B: pairwise N^2 outputs: k, tr_k_xj_xi, v_t_...; t21 into scratch.
// grid = N2/256 blocks of 256.
// ---------------------------------------------------------------------------
__global__ __launch_bounds__(256) void k_pairwise(
        const float* __restrict__ s1, float* __restrict__ s2,
        float* __restrict__ out_k, float* __restrict__ out_tr,
        float* __restrict__ out_vt)
{
    const int idx = blockIdx.x * 256 + threadIdx.x;   // exact: N2 % 256 == 0
    const int i = idx / NN, j = idx % NN;
    const float* X1 = s1;
    const float* R  = s1 + N2;
    const float* X3 = s1 + 2 * N2;
    const float* AV = s1 + 5 * N2;
    const float* BV = s1 + 6 * N2;

    float x1ij = X1[idx], x1ii = X1[i * NN + i], x1jj = X1[j * NN + j];
    float kv = expf(2.0f * x1ij - x1ii - x1jj);
    out_k[idx] = kv;

    float r_ij = R[idx], r_ii = R[i * NN + i], r_jj = R[j * NN + j];
    float gods = r_ii + r_jj - 2.0f * r_ij;
    out_tr[idx] = 2.0f * kv * (s2[NN] - 2.0f * gods);

    float av = AV[i * NN + i] - AV[idx];
    float bv = BV[i * NN + i] - BV[idx];
    out_vt[idx] = 2.0f * kv * (s2[i] - 2.0f * av * bv);

    float x3ij = X3[idx], x3ii = X3[i * NN + i], x3jj = X3[j * NN + j];
    s2[512 + idx] = x3ii + x3jj - 2.0f * x3ij;        // t2_1
}

// ---------------------------------------------------------------------------
// Kernel C: fused N^3 outputs.  Block = (i,a) pair, thread b over last axis.
// out4[i,m=a,j=b], out5[i,j=a,kk=b] share the Q/M quadratic form.
// ---------------------------------------------------------------------------
__global__ __launch_bounds__(NN) void k_big(
        const float* __restrict__ s1, const float* __restrict__ s2,
        const float* __restrict__ kmat,
        float* __restrict__ out4, float* __restrict__ out5)
{
    const int ia = blockIdx.x;
    const int i = ia / NN, a = ia % NN;
    const float* R   = s1 + N2;
    const float* P   = s1 + 3 * N2;
    const float* T   = s1 + 4 * N2;
    const float* t21 = s2 + 512;

    const float k_ia   = kmat[ia];
    const float S_ia   = T[a * NN + i] - T[a * NN + a];
    const float P_ai   = P[a * NN + i];
    const float R_ii   = R[i * NN + i];
    const float R_ia   = R[i * NN + a];
    const float t21_ia = t21[ia];
    const float g2s    = s2[NN + 1];

    const int b = threadIdx.x;
    const float k_ib   = kmat[i * NN + b];
    const float P_ab   = P[a * NN + b];
    const float R_ib   = R[i * NN + b];
    const float R_ab   = R[a * NN + b];
    const float t21_ib = t21[i * NN + b];

    const float Q   = R_ii - R_ib - R_ia + R_ab;   // == M for out5
    const float kk2 = k_ia * k_ib;
    const float Aa  = P_ai - P_ab;

    const long long o = (long long)ia * NN + b;
    out4[o] = kk2 * (8.0f * Aa * Q - 4.0f * S_ia);
    out5[o] = kk2 * (fmaf(16.0f * Q, Q, -8.0f * (t21_ia + t21_ib)) + 4.0f * g2s);
}

// ---------------------------------------------------------------------------
// Kernel D (runs LAST — overwrites the scratch regions): k_xj, k_xi.
// thread handles 4 consecutive d's -> float4 stores.
// ---------------------------------------------------------------------------
__global__ __launch_bounds__(256) void k_kxj(
        const float* __restrict__ x, const float* __restrict__ sigma,
        const float* __restrict__ kmat,
        float* __restrict__ out_kxj, float* __restrict__ out_kxi)
{
    const int tid  = blockIdx.x * 256 + threadIdx.x;  // N2*16 total, exact
    const int pair = tid >> 4;
    const int d0   = (tid & 15) << 2;
    const int i = pair / NN, j = pair % NN;

    const float kv2 = 2.0f * kmat[pair];
    float4 xi = *(const float4*)(x + i * DD + d0);
    float4 xj = *(const float4*)(x + j * DD + d0);
    float4 sg = *(const float4*)(sigma + d0);

    float4 r;
    r.x = kv2 * (1.0f / (2.0f * sg.x * sg.x + 1e-8f)) * (xi.x - xj.x);
    r.y = kv2 * (1.0f / (2.0f * sg.y * sg.y + 1e-8f)) * (xi.y - xj.y);
    r.z = kv2 * (1.0f / (2.0f * sg.z * sg.z + 1e-8f)) * (xi.z - xj.z);
    r.w = kv2 * (1.0f / (2.0f * sg.w * sg.w + 1e-8f)) * (xi.w - xj.w);

    const long long o = (long long)pair * DD + d0;
    *(float4*)(out_kxj + o) = r;
    float4 rn = { -r.x, -r.y, -r.z, -r.w };
    *(float4*)(out_kxi + o) = rn;
}

extern "C" void kernel_launch(void* const* d_in, const int* in_sizes, int n_in,
                              void* d_out, int out_size, void* d_ws, size_t ws_size,
                              hipStream_t stream) {
    const float* x     = (const float*)d_in[0];
    const float* sigma = (const float*)d_in[1];
    const float* score = (const float*)d_in[2];
    const float* v     = (const float*)d_in[3];
    const float* gvs   = (const float*)d_in[4];

    float* out = (float*)d_out;
    float* o_k   = out + O_K;
    float* o_kxj = out + O_KXJ;
    float* o_kxi = out + O_KXI;
    float* o_tr  = out + O_TR;
    float* o_s4  = out + O_S4;
    float* o_t5  = out + O_T5;
    float* o_vt  = out + O_VT;

    // scratch lives inside out1/out2 regions; k_kxj (last) overwrites them.
    float* s1 = o_kxj;   // 7*N2 = 716,800 floats  <  6,553,600
    float* s2 = o_kxi;   // c[320], gsum, g2sum, t21 at +512 (~103k floats)

    hipLaunchKernelGGL(k_matrices, dim3(NN), dim3(NN), 0, stream,
                       x, sigma, score, v, gvs, s1, s2);
    hipLaunchKernelGGL(k_pairwise, dim3(N2 / 256), dim3(256), 0, stream,
                       s1, s2, o_k, o_tr, o_vt);
    hipLaunchKernelGGL(k_big, dim3(N2), dim3(NN), 0, stream,
                       s1, s2, o_k, o_s4, o_t5);
    hipLaunchKernelGGL(k_kxj, dim3(N2 * 16 / 256), dim3(256), 0, stream,
                       x, sigma, o_k, o_kxj, o_kxi);
}

// Round 10
// 65.517 us; speedup vs baseline: 1.3371x; 1.3371x over previous
//
#include <hip/hip_runtime.h>

namespace {
constexpr int NN = 320;
constexpr int DD = 64;
constexpr int N2 = NN * NN;          // 102400
constexpr long long N2D = (long long)N2 * DD;   // 6,553,600
constexpr long long N3 = (long long)N2 * NN;    // 32,768,000

// output offsets (floats)
constexpr long long O_K   = 0;
constexpr long long O_KXJ = O_K + N2;            //   102,400
constexpr long long O_KXI = O_KXJ + N2D;         // 6,656,000
constexpr long long O_TR  = O_KXI + N2D;         // 13,209,600
constexpr long long O_S4  = O_TR + N2;           // 13,312,000
constexpr long long O_T5  = O_S4 + N3;           // 46,080,000
constexpr long long O_VT  = O_T5 + N3;           // 78,848,000

typedef float f32x4 __attribute__((ext_vector_type(4)));
}

// ---------------------------------------------------------------------------
// Kernel A: Gram matrices into scratch (= out1 region), c/scalars into out2
// grid = NN blocks, block = NN threads. Block i computes row i of 7 matrices.
// ---------------------------------------------------------------------------
__global__ __launch_bounds__(NN) void k_matrices(
        const float* __restrict__ x, const float* __restrict__ sigma,
        const float* __restrict__ score, const float* __restrict__ v,
        const float* __restrict__ gvs,
        float* __restrict__ s1,   // out1 region: 7 * N2 floats
        float* __restrict__ s2)   // out2 region: c[NN], gsum, g2sum
{
    __shared__ float xg[DD], xg2[DD], xg3[DD], sg[DD], sg2[DD], vg[DD], gg[DD];
    const int i = blockIdx.x;
    const int t = threadIdx.x;
    if (t < DD) {   // exactly wave 0
        float s  = sigma[t];
        float g  = 1.0f / (2.0f * s * s + 1e-8f);
        float g2 = g * g;
        float g3 = g2 * g;
        float xi = x[i * DD + t];
        xg[t]  = xi * g;  xg2[t] = xi * g2;  xg3[t] = xi * g3;
        float sc = score[i * DD + t];
        sg[t]  = sc * g;  sg2[t] = sc * g2;
        float vv = v[i * DD + t], gv = gvs[i * DD + t];
        vg[t] = vv * g;   gg[t] = gv * g;
        // c[i] = sum_d gamma*v*gvs  (64-lane wave reduce)
        float cp = g * vv * gv;
        #pragma unroll
        for (int off = 32; off; off >>= 1) cp += __shfl_down(cp, off, 64);
        if (t == 0) s2[i] = cp;
        if (i == 0) {
            float gs = g, g2s = g2;
            #pragma unroll
            for (int off = 32; off; off >>= 1) {
                gs  += __shfl_down(gs,  off, 64);
                g2s += __shfl_down(g2s, off, 64);
            }
            if (t == 0) { s2[NN] = gs; s2[NN + 1] = g2s; }
        }
    }
    __syncthreads();

    const int j = t;
    const float* xj = x + j * DD;
    float a1 = 0, a2 = 0, a3 = 0, a4 = 0, a5 = 0, a6 = 0, a7 = 0;
    #pragma unroll 8
    for (int d = 0; d < DD; ++d) {
        float xd = xj[d];
        a1 = fmaf(xg[d],  xd, a1);   // X1  = (x*g)   x^T
        a2 = fmaf(xg2[d], xd, a2);   // R   = (x*g2)  x^T
        a3 = fmaf(xg3[d], xd, a3);   // X3  = (x*g3)  x^T
        a4 = fmaf(sg[d],  xd, a4);   // P   = (sc*g)  x^T
        a5 = fmaf(sg2[d], xd, a5);   // T   = (sc*g2) x^T
        a6 = fmaf(vg[d],  xd, a6);   // AV  = (v*g)   x^T
        a7 = fmaf(gg[d],  xd, a7);   // BV  = (gvs*g) x^T
    }
    const int o = i * NN + j;
    s1[o]          = a1;
    s1[N2 + o]     = a2;
    s1[2 * N2 + o] = a3;
    s1[3 * N2 + o] = a4;
    s1[4 * N2 + o] = a5;
    s1[5 * N2 + o] = a6;
    s1[6 * N2 + o] = a7;
}

// ---------------------------------------------------------------------------
// Kernel B: pairwise N^2 outputs: k, tr_k_xj_xi, v_t_...; t21 into scratch.
// grid = N2/256 blocks of 256.
// ---------------------------------------------------------------------------
__global__ __launch_bounds__(256) void k_pairwise(
        const float* __restrict__ s1, float* __restrict__ s2,
        float* __restrict__ out_k, float* __restrict__ out_tr,
        float* __restrict__ out_vt)
{
    const int idx = blockIdx.x * 256 + threadIdx.x;   // exact: N2 % 256 == 0
    const int i = idx / NN, j = idx % NN;
    const float* X1 = s1;
    const float* R  = s1 + N2;
    const float* X3 = s1 + 2 * N2;
    const float* AV = s1 + 5 * N2;
    const float* BV = s1 + 6 * N2;

    float x1ij = X1[idx], x1ii = X1[i * NN + i], x1jj = X1[j * NN + j];
    float kv = expf(2.0f * x1ij - x1ii - x1jj);
    out_k[idx] = kv;

    float r_ij = R[idx], r_ii = R[i * NN + i], r_jj = R[j * NN + j];
    float gods = r_ii + r_jj - 2.0f * r_ij;
    out_tr[idx] = 2.0f * kv * (s2[NN] - 2.0f * gods);

    float av = AV[i * NN + i] - AV[idx];
    float bv = BV[i * NN + i] - BV[idx];
    out_vt[idx] = 2.0f * kv * (s2[i] - 2.0f * av * bv);

    float x3ij = X3[idx], x3ii = X3[i * NN + i], x3jj = X3[j * NN + j];
    s2[512 + idx] = x3ii + x3jj - 2.0f * x3ij;        // t2_1
}

// ---------------------------------------------------------------------------
// Kernel C: fused N^3 outputs, float4 per thread.
// Block = 4 (i,a) pairs x 80 float4-lanes (NN%4==0 -> same i within block).
// out4[i,m=a,j=b], out5[i,j=a,kk=b] share the Q/M quadratic form.
// ---------------------------------------------------------------------------
__global__ __launch_bounds__(NN) void k_big(
        const float* __restrict__ s1, const float* __restrict__ s2,
        const float* __restrict__ kmat,
        float* __restrict__ out4, float* __restrict__ out5)
{
    const int bid = blockIdx.x;            // 0 .. N2/4-1
    const int i   = bid / 80;              // 80 = NN/4 blocks per i-row
    const int a   = (bid % 80) * 4 + threadIdx.x / 80;
    const int b0  = (threadIdx.x % 80) * 4;

    const float* R   = s1 + N2;
    const float* P   = s1 + 3 * N2;
    const float* T   = s1 + 4 * N2;
    const float* t21 = s2 + 512;

    // per-pair scalars (broadcast loads across the 80 lanes of each q-group)
    const float k_ia   = kmat[i * NN + a];
    const float S_ia   = T[a * NN + i] - T[a * NN + a];
    const float P_ai   = P[a * NN + i];
    const float R_ii   = R[i * NN + i];
    const float R_ia   = R[i * NN + a];
    const float t21_ia = t21[i * NN + a];
    const float g2s    = s2[NN + 1];

    // vector operands
    const f32x4 kib  = *(const f32x4*)(kmat + i * NN + b0);
    const f32x4 Rib  = *(const f32x4*)(R    + i * NN + b0);
    const f32x4 t21b = *(const f32x4*)(t21  + i * NN + b0);
    const f32x4 Pab  = *(const f32x4*)(P    + a * NN + b0);
    const f32x4 Rab  = *(const f32x4*)(R    + a * NN + b0);

    f32x4 o4, o5;
    #pragma unroll
    for (int q = 0; q < 4; ++q) {
        float Q   = R_ii - Rib[q] - R_ia + Rab[q];
        float kk2 = k_ia * kib[q];
        o4[q] = kk2 * (8.0f * (P_ai - Pab[q]) * Q - 4.0f * S_ia);
        o5[q] = kk2 * (fmaf(16.0f * Q, Q, -8.0f * (t21_ia + t21b[q])) + 4.0f * g2s);
    }

    const long long o = ((long long)(i * NN + a)) * NN + b0;
    __builtin_nontemporal_store(o4, (f32x4*)(out4 + o));
    __builtin_nontemporal_store(o5, (f32x4*)(out5 + o));
}

// ---------------------------------------------------------------------------
// Kernel D (runs LAST — overwrites the scratch regions): k_xj, k_xi.
// thread handles 4 consecutive d's -> float4 stores.
// ---------------------------------------------------------------------------
__global__ __launch_bounds__(256) void k_kxj(
        const float* __restrict__ x, const float* __restrict__ sigma,
        const float* __restrict__ kmat,
        float* __restrict__ out_kxj, float* __restrict__ out_kxi)
{
    const int tid  = blockIdx.x * 256 + threadIdx.x;  // N2*16 total, exact
    const int pair = tid >> 4;
    const int d0   = (tid & 15) << 2;
    const int i = pair / NN, j = pair % NN;

    const float kv2 = 2.0f * kmat[pair];
    const f32x4 xi = *(const f32x4*)(x + i * DD + d0);
    const f32x4 xj = *(const f32x4*)(x + j * DD + d0);
    const f32x4 sg = *(const f32x4*)(sigma + d0);

    f32x4 r;
    #pragma unroll
    for (int q = 0; q < 4; ++q)
        r[q] = kv2 * (1.0f / (2.0f * sg[q] * sg[q] + 1e-8f)) * (xi[q] - xj[q]);

    const long long o = (long long)pair * DD + d0;
    __builtin_nontemporal_store(r, (f32x4*)(out_kxj + o));
    f32x4 rn = -r;
    __builtin_nontemporal_store(rn, (f32x4*)(out_kxi + o));
}

extern "C" void kernel_launch(void* const* d_in, const int* in_sizes, int n_in,
                              void* d_out, int out_size, void* d_ws, size_t ws_size,
                              hipStream_t stream) {
    const float* x     = (const float*)d_in[0];
    const float* sigma = (const float*)d_in[1];
    const float* score = (const float*)d_in[2];
    const float* v     = (const float*)d_in[3];
    const float* gvs   = (const float*)d_in[4];

    float* out = (float*)d_out;
    float* o_k   = out + O_K;
    float* o_kxj = out + O_KXJ;
    float* o_kxi = out + O_KXI;
    float* o_tr  = out + O_TR;
    float* o_s4  = out + O_S4;
    float* o_t5  = out + O_T5;
    float* o_vt  = out + O_VT;

    // scratch lives inside out1/out2 regions; k_kxj (last) overwrites them.
    float* s1 = o_kxj;   // 7*N2 = 716,800 floats  <  6,553,600
    float* s2 = o_kxi;   // c[320], gsum, g2sum, t21 at +512 (~103k floats)

    hipLaunchKernelGGL(k_matrices, dim3(NN), dim3(NN), 0, stream,
                       x, sigma, score, v, gvs, s1, s2);
    hipLaunchKernelGGL(k_pairwise, dim3(N2 / 256), dim3(256), 0, stream,
                       s1, s2, o_k, o_tr, o_vt);
    hipLaunchKernelGGL(k_big, dim3(N2 / 4), dim3(NN), 0, stream,
                       s1, s2, o_k, o_s4, o_t5);
    hipLaunchKernelGGL(k_kxj, dim3(N2 * 16 / 256), dim3(256), 0, stream,
                       x, sigma, o_k, o_kxj, o_kxi);
}